// Round 1
// 540.920 us; speedup vs baseline: 1.2073x; 1.2073x over previous
//
#include <hip/hip_runtime.h>
#include <hip/hip_bf16.h>

#define HW 512
#define IC 64
#define OC 64
#define NB 4

#define SROW 66            /* staged px per row: 64 + 2 halo */
#define CPR (SROW * 8)     /* 16B chunks per staged row = 528 */
#define NCHUNK (6 * CPR)   /* 3168 chunks = 50688 B LDS */

typedef short s16x8 __attribute__((ext_vector_type(8)));
typedef float f32x16 __attribute__((ext_vector_type(16)));

// ---------------------------------------------------------------------------
// Kernel 1: style modulation + demodulation.
// Output layout re-blocked for coalesced MFMA A-fragment loads:
//   wd[b][tap][g][o][e]  where ch = g*8 + e   (g = 0..7, e = 0..7)
// A lane (o = mt*32 + lane&31, k-group g = ks*2 + lane>>5) then reads a
// contiguous 16B at offset ((tap*8+g)*64 + o)*8 -> 512B/wave, fully coalesced.
// ---------------------------------------------------------------------------
__global__ __launch_bounds__(64) void demod_kernel(
    const float* __restrict__ weight,   // [O][I][3][3]
    const float* __restrict__ style,    // [B][I]
    __hip_bfloat16* __restrict__ wd)    // [B][9][8][OC][8]
{
    const int bo = blockIdx.x;
    const int b = bo >> 6;
    const int o = bo & 63;
    const int i = threadIdx.x;          // input channel

    const float st = style[b * IC + i];
    float v[9];
    float s = 0.f;
#pragma unroll
    for (int t = 0; t < 9; ++t) {
        const float w = weight[(o * IC + i) * 9 + t] * st;
        v[t] = w;
        s += w * w;
    }
#pragma unroll
    for (int off = 32; off >= 1; off >>= 1) s += __shfl_xor(s, off);
    const float rs = 1.0f / sqrtf(1e-8f + s);
#pragma unroll
    for (int t = 0; t < 9; ++t)
        wd[(((b * 9 + t) * 8 + (i >> 3)) * OC + o) * 8 + (i & 7)] =
            __float2bfloat16(v[t] * rs);
}

// ---------------------------------------------------------------------------
// Kernel 2: NCHW fp32 -> NHWC bf16 (unchanged).
// ---------------------------------------------------------------------------
__global__ __launch_bounds__(256) void nchw_to_nhwc_bf16(
    const float* __restrict__ in,       // [B][I][H][W]
    __hip_bfloat16* __restrict__ t)     // [B][H][W][I]
{
    __shared__ unsigned short lds[64 * 130];
    const int tid = threadIdx.x;
    const int xb = blockIdx.x * 128;
    const int y = blockIdx.y;
    const int b = blockIdx.z;

#pragma unroll
    for (int it = 0; it < 8; ++it) {
        const int idx = it * 256 + tid;
        const int i = idx >> 5;
        const int xq = idx & 31;
        const float4 v = *(const float4*)(in +
            (((long)(b * IC + i) * HW + y) * HW + xb + xq * 4));
        __hip_bfloat16 h0 = __float2bfloat16(v.x), h1 = __float2bfloat16(v.y);
        __hip_bfloat16 h2 = __float2bfloat16(v.z), h3 = __float2bfloat16(v.w);
        unsigned p01 = ((unsigned)*(unsigned short*)&h1 << 16) | *(unsigned short*)&h0;
        unsigned p23 = ((unsigned)*(unsigned short*)&h3 << 16) | *(unsigned short*)&h2;
        *(unsigned*)&lds[i * 130 + xq * 4] = p01;
        *(unsigned*)&lds[i * 130 + xq * 4 + 2] = p23;
    }
    __syncthreads();
    unsigned short* tp = (unsigned short*)t;
#pragma unroll
    for (int it = 0; it < 4; ++it) {
        const int idx = it * 256 + tid;
        const int x = idx >> 3;
        const int g = idx & 7;
        unsigned r[4];
#pragma unroll
        for (int cp = 0; cp < 4; ++cp) {
            unsigned lo = lds[(g * 8 + cp * 2) * 130 + x];
            unsigned hi = lds[(g * 8 + cp * 2 + 1) * 130 + x];
            r[cp] = (hi << 16) | lo;
        }
        uint4 o4 = {r[0], r[1], r[2], r[3]};
        *(uint4*)(tp + (((long)(b * HW + y) * HW + xb + x) * IC + g * 8)) = o4;
    }
}

// ---------------------------------------------------------------------------
// async global -> LDS, 16B per lane.  LDS dest is linear (base + lane*16);
// swizzle is achieved by permuting the GLOBAL source address (rule #21).
// ---------------------------------------------------------------------------
__device__ __forceinline__ void gload_lds16(const void* g, void* l) {
    __builtin_amdgcn_global_load_lds(
        (const __attribute__((address_space(1))) unsigned*)(unsigned long long)g,
        (__attribute__((address_space(3))) unsigned*)(unsigned)(unsigned long long)l,
        16, 0, 0);
}

// ---------------------------------------------------------------------------
// Kernel 3: implicit-GEMM conv, v2.
//   Tile: 64 O x 64 px x 4 rows.  4 waves, wave w owns output row ybase+w.
//   LDS: 6 rows x 66 px x 64 ch bf16, chunked in 16B units of 8 channels.
//   Chunk (r,px,cg) lives at slot cg ^ (px&7)  -> ds_read_b128 is 2-way (free).
//   Staged once (full K=64), single barrier, then 144 mfma_32x32x16 per wave.
// ---------------------------------------------------------------------------
__global__ __launch_bounds__(256, 3) void conv_mfma(
    const __hip_bfloat16* __restrict__ tin,  // [B][H][W][I]
    const __hip_bfloat16* __restrict__ wd,   // [B][9][8][OC][8]
    float* __restrict__ out)                 // [B][O][H][W]
{
    __shared__ __align__(16) unsigned short bin[NCHUNK * 8];  // 50688 B

    const int tid = threadIdx.x;
    const int wave = tid >> 6, lane = tid & 63;
    const int l31 = lane & 31, hi = lane >> 5;

    // XCD swizzle: xcd = id&7 -> (b, y-half); slots walk x fastest, then y
    const int id = blockIdx.x;               // 0..4095
    const int xcd = id & 7, slot = id >> 3;  // slot 0..511
    const int b = xcd >> 1;
    const int xb = (slot & 7) << 6;                            // 0..448
    const int ybase = ((xcd & 1) << 8) | ((slot >> 3) << 2);   // 0..508 step 4

    const unsigned short* tb = (const unsigned short*)tin + (long)b * HW * HW * IC;
    const unsigned short* wp = (const unsigned short*)wd + b * 9 * 8 * OC * 8;

    // ---- stage 6 rows x 66 px x 64 ch via global_load_lds (3168 chunks) ----
    // last iter re-covers chunks 2912..3167 (160 dup loads, same data: benign)
#pragma unroll
    for (int it = 0; it < 13; ++it) {
        const int n = (it == 12) ? (NCHUNK - 256 + tid) : (it * 256 + tid);
        const int r = n / CPR;
        const int q = n - r * CPR;
        const int px = q >> 3, sl = q & 7;
        const int cg = sl ^ (px & 7);            // inverse swizzle on source
        int xg = xb + px - 1; xg = xg < 0 ? 0 : (xg > HW - 1 ? HW - 1 : xg);
        int yg = ybase + r - 1; yg = yg < 0 ? 0 : (yg > HW - 1 ? HW - 1 : yg);
        const unsigned short* src = tb + ((long)yg * HW + xg) * IC + cg * 8;
        gload_lds16(src, &bin[n * 8]);
    }
    __syncthreads();

    // ---- zero OOB halo (edge blocks only; clamped loads held garbage) ----
    if (ybase == 0 || ybase == HW - 4 || xb == 0 || xb == HW - 64) {
        const uint4 z = {0u, 0u, 0u, 0u};
        if (ybase == 0) {
#pragma unroll
            for (int k = 0; k < 3; ++k) {
                const int q = k * 256 + tid;
                if (q < CPR) *(uint4*)&bin[q * 8] = z;
            }
        }
        if (ybase == HW - 4) {
#pragma unroll
            for (int k = 0; k < 3; ++k) {
                const int q = k * 256 + tid;
                if (q < CPR) *(uint4*)&bin[(5 * CPR + q) * 8] = z;
            }
        }
        if (xb == 0 && tid < 48)
            *(uint4*)&bin[((tid >> 3) * CPR + (tid & 7)) * 8] = z;
        if (xb == HW - 64 && tid < 48)
            *(uint4*)&bin[((tid >> 3) * CPR + 65 * 8 + (tid & 7)) * 8] = z;
        __syncthreads();
    }

    // ---- 9 taps x 4 K-steps of mfma_f32_32x32x16_bf16 ----
    f32x16 acc[2][2];
#pragma unroll
    for (int mt = 0; mt < 2; ++mt)
#pragma unroll
        for (int nt = 0; nt < 2; ++nt)
#pragma unroll
            for (int e = 0; e < 16; ++e) acc[mt][nt][e] = 0.f;

#pragma unroll
    for (int ky = 0; ky < 3; ++ky) {
        const int rr = (wave + ky) * SROW;
#pragma unroll
        for (int kx = 0; kx < 3; ++kx) {
            const int tap = ky * 3 + kx;
            const int e7 = (l31 + kx) & 7;
#pragma unroll
            for (int ks = 0; ks < 4; ++ks) {
                const int cg = ks * 2 + hi;      // channel group 0..7
                const int sl = cg ^ e7;          // swizzled read slot
                s16x8 af[2], bf[2];
#pragma unroll
                for (int mt = 0; mt < 2; ++mt)
                    af[mt] = *(const s16x8*)(wp + (tap * 8 + cg) * 512 +
                                             (mt * 32 + l31) * 8);
#pragma unroll
                for (int nt = 0; nt < 2; ++nt) {
                    const int s = nt * 32 + l31 + kx;   // staged px 0..65
                    bf[nt] = *(const s16x8*)(&bin[((rr + s) * 8 + sl) * 8]);
                }
#pragma unroll
                for (int mt = 0; mt < 2; ++mt)
#pragma unroll
                    for (int nt = 0; nt < 2; ++nt)
                        acc[mt][nt] = __builtin_amdgcn_mfma_f32_32x32x16_bf16(
                            af[mt], bf[nt], acc[mt][nt], 0, 0, 0);
            }
        }
    }

    // ---- epilogue: 32x32 C layout: col = lane&31, row = r + 8g + 4hi ----
    const int y = ybase + wave;
#pragma unroll
    for (int mt = 0; mt < 2; ++mt) {
#pragma unroll
        for (int g = 0; g < 4; ++g) {
#pragma unroll
            for (int r = 0; r < 4; ++r) {
                const int o = mt * 32 + r + g * 8 + hi * 4;
                float* orow = out + ((long)(b * OC + o) * HW + y) * HW + xb;
#pragma unroll
                for (int nt = 0; nt < 2; ++nt)
                    orow[nt * 32 + l31] = acc[mt][nt][g * 4 + r];
            }
        }
    }
}

// ---------------------------------------------------------------------------
extern "C" void kernel_launch(void* const* d_in, const int* in_sizes, int n_in,
                              void* d_out, int out_size, void* d_ws, size_t ws_size,
                              hipStream_t stream) {
    const float* inp = (const float*)d_in[0];     // [4][64][512][512]
    const float* style = (const float*)d_in[1];   // [4][64]
    const float* weight = (const float*)d_in[2];  // [64][64][3][3]
    float* out = (float*)d_out;                   // [4][64][512][512]

    __hip_bfloat16* wd = (__hip_bfloat16*)d_ws;                       // 294,912 B
    __hip_bfloat16* tin = (__hip_bfloat16*)((char*)d_ws + 0x60000);   // 128 MB

    demod_kernel<<<dim3(NB * OC), dim3(64), 0, stream>>>(weight, style, wd);
    nchw_to_nhwc_bf16<<<dim3(HW / 128, HW, NB), dim3(256), 0, stream>>>(inp, tin);
    conv_mfma<<<dim3(NB * HW * 2), dim3(256), 0, stream>>>(tin, wd, out);
}

// Round 2
// 498.989 us; speedup vs baseline: 1.3088x; 1.0840x over previous
//
#include <hip/hip_runtime.h>
#include <hip/hip_bf16.h>

#define HW 512
#define IC 64
#define OC 64
#define NB 4

#define SROW 66            /* staged px per row: 64 + 2 halo */

typedef short s16x8 __attribute__((ext_vector_type(8)));
typedef float f32x16 __attribute__((ext_vector_type(16)));

// ---------------------------------------------------------------------------
// Kernel 1: style modulation + demodulation.
//   wd[b][tap][g][o][e]  where ch = g*8 + e   (g = 0..7, e = 0..7)
// A lane (o = mt*32 + lane&31, k-group g = ks*2 + lane>>5) reads a contiguous
// 16B at ((tap*8+g)*64 + o)*8 -> 512B/wave, fully coalesced.
// ---------------------------------------------------------------------------
__global__ __launch_bounds__(64) void demod_kernel(
    const float* __restrict__ weight,   // [O][I][3][3]
    const float* __restrict__ style,    // [B][I]
    __hip_bfloat16* __restrict__ wd)    // [B][9][8][OC][8]
{
    const int bo = blockIdx.x;
    const int b = bo >> 6;
    const int o = bo & 63;
    const int i = threadIdx.x;          // input channel

    const float st = style[b * IC + i];
    float v[9];
    float s = 0.f;
#pragma unroll
    for (int t = 0; t < 9; ++t) {
        const float w = weight[(o * IC + i) * 9 + t] * st;
        v[t] = w;
        s += w * w;
    }
#pragma unroll
    for (int off = 32; off >= 1; off >>= 1) s += __shfl_xor(s, off);
    const float rs = 1.0f / sqrtf(1e-8f + s);
#pragma unroll
    for (int t = 0; t < 9; ++t)
        wd[(((b * 9 + t) * 8 + (i >> 3)) * OC + o) * 8 + (i & 7)] =
            __float2bfloat16(v[t] * rs);
}

// ---------------------------------------------------------------------------
static __device__ __forceinline__ unsigned short bf16_bits(float f) {
    __hip_bfloat16 h = __float2bfloat16(f);
    return *(unsigned short*)&h;
}
static __device__ __forceinline__ unsigned pack2(float lo, float hi) {
    return ((unsigned)bf16_bits(hi) << 16) | (unsigned)bf16_bits(lo);
}

// ---------------------------------------------------------------------------
// Kernel 2: FUSED layout-transform + implicit-GEMM conv.
//   Tile: 64 O x 64 px x 4 rows.  4 waves, wave w owns output row ybase+w.
//   Staging reads fp32 NCHW directly (register transpose + bf16 convert),
//   writing the same XOR-swizzled LDS layout the MFMA loop already uses:
//   chunk (r,px,cg) at slot cg ^ (px&7)  -> all LDS traffic 2-way (free).
//   Lane map for staging: g = lane>>2 (px-quad), qi = lane&3 (ch-octet) so
//   quarter-wave ds_write_b128 spans all 8 slots x2 lanes (conflict-free);
//   global loads remain 4x256B contiguous segments per instruction.
//   OOB halo written as zeros inline -> single barrier, no fixup pass.
// ---------------------------------------------------------------------------
__global__ __launch_bounds__(256, 3) void conv_mfma(
    const float* __restrict__ in,            // [B][I][H][W] fp32
    const __hip_bfloat16* __restrict__ wd,   // [B][9][8][OC][8]
    float* __restrict__ out)                 // [B][O][H][W]
{
    __shared__ __align__(16) unsigned short bin[6 * SROW * 8 * 8];  // 50688 B

    const int tid = threadIdx.x;
    const int wave = tid >> 6, lane = tid & 63;
    const int l31 = lane & 31, hi = lane >> 5;

    // XCD swizzle: xcd = id&7 -> (b, y-half); slots walk x fastest, then y
    const int id = blockIdx.x;               // 0..4095
    const int xcd = id & 7, slot = id >> 3;  // slot 0..511
    const int b = xcd >> 1;
    const int xb = (slot & 7) << 6;                            // 0..448
    const int ybase = ((xcd & 1) << 8) | ((slot >> 3) << 2);   // 0..508 step 4

    const float* ib = in + (long)b * IC * HW * HW;
    const unsigned short* wp = (const unsigned short*)wd + b * 9 * 8 * OC * 8;

    // ---- staging: core px 1..64 (x = xb .. xb+63), register transpose ----
    {
        const int g = lane >> 2;             // px-quad 0..15
        const int qi = lane & 3;
#pragma unroll
        for (int it = 0; it < 3; ++it) {
            const int idx = it * 4 + wave;           // 0..11
            const int r = idx >> 1;                  // staged row 0..5
            const int q = ((idx & 1) << 2) | qi;     // ch octet 0..7
            const int yg = ybase + r - 1;
            float4 v[8];
            if ((unsigned)yg < (unsigned)HW) {
                const float* src = ib + ((long)(q * 8) * HW + yg) * HW + xb + g * 4;
#pragma unroll
                for (int c = 0; c < 8; ++c)
                    v[c] = *(const float4*)(src + (long)c * HW * HW);
            } else {
#pragma unroll
                for (int c = 0; c < 8; ++c) v[c] = make_float4(0.f, 0.f, 0.f, 0.f);
            }
#pragma unroll
            for (int j = 0; j < 4; ++j) {
                const int px = g * 4 + 1 + j;        // staged px 1..64
                const int sl = q ^ (px & 7);
                float e[8];
#pragma unroll
                for (int c = 0; c < 8; ++c)
                    e[c] = (j == 0) ? v[c].x : (j == 1) ? v[c].y
                         : (j == 2) ? v[c].z : v[c].w;
                uint4 o4 = { pack2(e[0], e[1]), pack2(e[2], e[3]),
                             pack2(e[4], e[5]), pack2(e[6], e[7]) };
                *(uint4*)&bin[((r * SROW + px) * 8 + sl) * 8] = o4;
            }
        }
    }
    // ---- staging: halo columns px 0 (x=xb-1) and px 65 (x=xb+64) ----
    if (tid < 96) {
        const int e_ = tid & 1;
        const int rq = tid >> 1;                 // 0..47
        const int r = rq >> 3, q = rq & 7;
        const int x = e_ ? (xb + 64) : (xb - 1);
        const int yg = ybase + r - 1;
        const bool ok = ((unsigned)x < (unsigned)HW) & ((unsigned)yg < (unsigned)HW);
        float f[8];
#pragma unroll
        for (int c = 0; c < 8; ++c) {
            f[c] = 0.f;
            if (ok) f[c] = ib[((long)(q * 8 + c) * HW + yg) * HW + x];
        }
        const int px = e_ ? 65 : 0;
        const int sl = q ^ (px & 7);
        uint4 o4 = { pack2(f[0], f[1]), pack2(f[2], f[3]),
                     pack2(f[4], f[5]), pack2(f[6], f[7]) };
        *(uint4*)&bin[((r * SROW + px) * 8 + sl) * 8] = o4;
    }
    __syncthreads();

    // ---- 9 taps x 4 K-steps of mfma_f32_32x32x16_bf16 ----
    f32x16 acc[2][2];
#pragma unroll
    for (int mt = 0; mt < 2; ++mt)
#pragma unroll
        for (int nt = 0; nt < 2; ++nt)
#pragma unroll
            for (int e = 0; e < 16; ++e) acc[mt][nt][e] = 0.f;

#pragma unroll
    for (int ky = 0; ky < 3; ++ky) {
        const int rr = (wave + ky) * SROW;
#pragma unroll
        for (int kx = 0; kx < 3; ++kx) {
            const int tap = ky * 3 + kx;
            const int e7 = (l31 + kx) & 7;
#pragma unroll
            for (int ks = 0; ks < 4; ++ks) {
                const int cg = ks * 2 + hi;      // channel group 0..7
                const int sl = cg ^ e7;          // swizzled read slot
                s16x8 af[2], bf[2];
#pragma unroll
                for (int mt = 0; mt < 2; ++mt)
                    af[mt] = *(const s16x8*)(wp + (tap * 8 + cg) * 512 +
                                             (mt * 32 + l31) * 8);
#pragma unroll
                for (int nt = 0; nt < 2; ++nt) {
                    const int s = nt * 32 + l31 + kx;   // staged px 0..65
                    bf[nt] = *(const s16x8*)(&bin[((rr + s) * 8 + sl) * 8]);
                }
#pragma unroll
                for (int mt = 0; mt < 2; ++mt)
#pragma unroll
                    for (int nt = 0; nt < 2; ++nt)
                        acc[mt][nt] = __builtin_amdgcn_mfma_f32_32x32x16_bf16(
                            af[mt], bf[nt], acc[mt][nt], 0, 0, 0);
            }
        }
    }

    // ---- epilogue: 32x32 C layout: col = lane&31, row = r + 8g + 4hi ----
    const int y = ybase + wave;
#pragma unroll
    for (int mt = 0; mt < 2; ++mt) {
#pragma unroll
        for (int g = 0; g < 4; ++g) {
#pragma unroll
            for (int r = 0; r < 4; ++r) {
                const int o = mt * 32 + r + g * 8 + hi * 4;
                float* orow = out + ((long)(b * OC + o) * HW + y) * HW + xb;
#pragma unroll
                for (int nt = 0; nt < 2; ++nt)
                    orow[nt * 32 + l31] = acc[mt][nt][g * 4 + r];
            }
        }
    }
}

// ---------------------------------------------------------------------------
extern "C" void kernel_launch(void* const* d_in, const int* in_sizes, int n_in,
                              void* d_out, int out_size, void* d_ws, size_t ws_size,
                              hipStream_t stream) {
    const float* inp = (const float*)d_in[0];     // [4][64][512][512]
    const float* style = (const float*)d_in[1];   // [4][64]
    const float* weight = (const float*)d_in[2];  // [64][64][3][3]
    float* out = (float*)d_out;                   // [4][64][512][512]

    __hip_bfloat16* wd = (__hip_bfloat16*)d_ws;   // 294,912 B

    demod_kernel<<<dim3(NB * OC), dim3(64), 0, stream>>>(weight, style, wd);
    conv_mfma<<<dim3(NB * HW * 2), dim3(256), 0, stream>>>(inp, wd, out);
}